// Round 1
// baseline (419.950 us; speedup 1.0000x reference)
//
#include <hip/hip_runtime.h>
#include <hip/hip_bf16.h>
#include <math.h>

#define Bn 8
#define Cn 96
#define Hn 128
#define Wn 128
#define PLANE (Hn*Wn)          // 16384
#define NIMG (Bn*Cn*PLANE)     // 12582912
#define EPSV 1e-5f

// ---------------------------------------------------------------------------
// K1: t = m + l = 2x + axialH(rm) + axialW(rm) + axialH(rl) + axialW(rl)
// ---------------------------------------------------------------------------
__device__ __forceinline__ float axial_h(const float* pl, int h, int w, float r, const float* tap) {
    float a = 0.f;
#pragma unroll
    for (int i = 0; i < 5; ++i) {
        float s = (float)(i - 2) * r;
        float f = floorf(s);
        float fr = s - f;
        int fi = (int)f;
        int y0 = h + fi, y1 = y0 + 1;
        float v0 = (y0 >= 0 && y0 < Hn) ? pl[(y0 << 7) + w] : 0.f;
        float v1 = (y1 >= 0 && y1 < Hn) ? pl[(y1 << 7) + w] : 0.f;
        a += tap[i] * ((1.f - fr) * v0 + fr * v1);
    }
    return a;
}

__device__ __forceinline__ float axial_w(const float* pl, int h, int w, float r, const float* tap) {
    float a = 0.f;
#pragma unroll
    for (int i = 0; i < 5; ++i) {
        float s = (float)(i - 2) * r;
        float f = floorf(s);
        float fr = s - f;
        int fi = (int)f;
        int x0 = w + fi, x1 = x0 + 1;
        float v0 = (x0 >= 0 && x0 < Wn) ? pl[(h << 7) + x0] : 0.f;
        float v1 = (x1 >= 0 && x1 < Wn) ? pl[(h << 7) + x1] : 0.f;
        a += tap[i] * ((1.f - fr) * v0 + fr * v1);
    }
    return a;
}

__global__ __launch_bounds__(256) void k1_axial(
    const float* __restrict__ x,
    const float* __restrict__ rm_p, const float* __restrict__ whm, const float* __restrict__ wwm,
    const float* __restrict__ rl_p, const float* __restrict__ whl, const float* __restrict__ wwl,
    float* __restrict__ t_out)
{
    int idx = blockIdx.x * 256 + threadIdx.x;
    if (idx >= NIMG) return;
    int w = idx & 127;
    int h = (idx >> 7) & 127;
    int bc = idx >> 14;           // 0..767
    int c = bc % Cn;
    const float* pl = x + ((long)bc << 14);
    float rm = fmaxf(rm_p[0], 1.f);
    float rl = fmaxf(rl_p[0], 1.f);
    float center = pl[(h << 7) + w];
    float acc = 2.f * center;
    acc += axial_h(pl, h, w, rm, whm + c * 5);
    acc += axial_w(pl, h, w, rm, wwm + c * 5);
    acc += axial_h(pl, h, w, rl, whl + c * 5);
    acc += axial_w(pl, h, w, rl, wwl + c * 5);
    t_out[idx] = acc;
}

// ---------------------------------------------------------------------------
// K2: out_pre = prelu( BN(w_fuse @ t) + BN(x + edges), act_a )
// Block: 64 consecutive pixels (one half-row, single h) x all 96 channels.
// ---------------------------------------------------------------------------
__global__ __launch_bounds__(256) void k2_pw(
    const float* __restrict__ t_g, const float* __restrict__ x,
    const float* __restrict__ w_fuse,
    const float* __restrict__ bg, const float* __restrict__ bb,
    const float* __restrict__ bm, const float* __restrict__ bv,
    const float* __restrict__ dwh, const float* __restrict__ dww,
    const float* __restrict__ dg, const float* __restrict__ db_,
    const float* __restrict__ dm, const float* __restrict__ dv,
    const float* __restrict__ act_a,
    float* __restrict__ out_pre)
{
    __shared__ float tl[Cn * 64];        // 24 KB
    __shared__ float wl[Cn * 97];        // 37.2 KB (pad 96->97 kills bank conflicts)
    int tid = threadIdx.x;
    int blk = blockIdx.x;                // 2048
    int b  = blk >> 8;
    int p0 = (blk & 255) * 64;
    int h  = p0 >> 7;
    int w0 = p0 & 127;
    long base_b = (long)b * Cn * PLANE;

    for (int e = tid; e < Cn * Cn; e += 256) {
        int o = e / Cn;
        int c = e - o * Cn;
        wl[o * 97 + c] = w_fuse[e];
    }
    for (int e = tid; e < Cn * 64; e += 256) {
        int c = e >> 6;
        int p = e & 63;
        tl[c * 64 + p] = t_g[base_b + c * PLANE + p0 + p];
    }
    __syncthreads();

    int pix4 = tid & 15;     // 4 consecutive pixels: wc..wc+3
    int og   = tid >> 4;     // 16 groups x 6 output channels
    float acc[6][4];
#pragma unroll
    for (int j = 0; j < 6; ++j)
#pragma unroll
        for (int k = 0; k < 4; ++k) acc[j][k] = 0.f;

    for (int c = 0; c < Cn; ++c) {
        float4 tv = *(const float4*)&tl[c * 64 + pix4 * 4];
#pragma unroll
        for (int j = 0; j < 6; ++j) {
            float wv = wl[(og * 6 + j) * 97 + c];
            acc[j][0] += wv * tv.x;
            acc[j][1] += wv * tv.y;
            acc[j][2] += wv * tv.z;
            acc[j][3] += wv * tv.w;
        }
    }

    int wc = w0 + pix4 * 4;
#pragma unroll
    for (int j = 0; j < 6; ++j) {
        int o = og * 6 + j;
        const float* xp = x + base_b + (long)o * PLANE + (h << 7) + wc;
        float4 cx = *(const float4*)xp;
        float4 up = (h > 0)       ? *(const float4*)(xp - Wn) : make_float4(0, 0, 0, 0);
        float4 dn = (h < Hn - 1)  ? *(const float4*)(xp + Wn) : make_float4(0, 0, 0, 0);
        float lf = (wc > 0)       ? xp[-1] : 0.f;
        float rt = (wc + 4 < Wn)  ? xp[4]  : 0.f;
        float cxa[4] = {cx.x, cx.y, cx.z, cx.w};
        float upa[4] = {up.x, up.y, up.z, up.w};
        float dna[4] = {dn.x, dn.y, dn.z, dn.w};
        float lva[4] = {lf, cx.x, cx.y, cx.z};
        float rva[4] = {cx.y, cx.z, cx.w, rt};
        float wh0 = dwh[o * 3], wh1 = dwh[o * 3 + 1], wh2 = dwh[o * 3 + 2];
        float ww0 = dww[o * 3], ww1 = dww[o * 3 + 1], ww2 = dww[o * 3 + 2];
        float dsc = dg[o] * rsqrtf(dv[o] + EPSV);
        float dof = db_[o] - dm[o] * dsc;
        float fsc = bg[o] * rsqrtf(bv[o] + EPSV);
        float fof = bb[o] - bm[o] * fsc;
        float aa  = act_a[o];
        float4 res;
        float r4[4];
#pragma unroll
        for (int k = 0; k < 4; ++k) {
            float edges = wh0 * upa[k] + wh1 * cxa[k] + wh2 * dna[k]
                        + ww0 * lva[k] + ww1 * cxa[k] + ww2 * rva[k];
            float anch = (cxa[k] + edges) * dsc + dof;
            float fused = acc[j][k] * fsc + fof;
            float v = fused + anch;
            r4[k] = (v >= 0.f) ? v : aa * v;
        }
        res.x = r4[0]; res.y = r4[1]; res.z = r4[2]; res.w = r4[3];
        *(float4*)&out_pre[base_b + (long)o * PLANE + (h << 7) + wc] = res;
    }
}

// ---------------------------------------------------------------------------
// K3: per-(b,c) plane: row means (over w) -> xh, column means (over h) -> xw
// ---------------------------------------------------------------------------
__global__ __launch_bounds__(128) void k3_means(
    const float* __restrict__ op, float* __restrict__ xh, float* __restrict__ xw)
{
    int bc = blockIdx.x;                 // 768
    const float* pl = op + ((long)bc << 14);
    int tid = threadIdx.x;               // 128
    int lane = tid & 63, wid = tid >> 6;
    __shared__ float part[Hn * 2];
    float colsum = 0.f;
    for (int h = 0; h < Hn; ++h) {
        float v = pl[(h << 7) + tid];
        colsum += v;
        float r = v;
#pragma unroll
        for (int off = 32; off; off >>= 1) r += __shfl_down(r, off, 64);
        if (lane == 0) part[h * 2 + wid] = r;
    }
    __syncthreads();
    xw[bc * Wn + tid] = colsum * (1.f / Hn);
    xh[bc * Hn + tid] = (part[tid * 2] + part[tid * 2 + 1]) * (1.f / Wn);
}

// ---------------------------------------------------------------------------
// K4: coord-attention MLP: y2 = prelu(BN(ca_w1 @ [xh;xw])); a = sigmoid(W @ y2)
// ---------------------------------------------------------------------------
__global__ __launch_bounds__(256) void k4_att(
    const float* __restrict__ xh, const float* __restrict__ xw,
    const float* __restrict__ w1,
    const float* __restrict__ g, const float* __restrict__ bb,
    const float* __restrict__ m, const float* __restrict__ v,
    const float* __restrict__ aa,
    const float* __restrict__ cwh, const float* __restrict__ cww,
    float* __restrict__ a_h, float* __restrict__ a_w)
{
    int b = blockIdx.x;      // 8
    int p = threadIdx.x;     // 256 = H + W positions
    __shared__ float w1s[8 * Cn];
    __shared__ float whs[Cn * 8];
    __shared__ float wws[Cn * 8];
    for (int e = p; e < 8 * Cn; e += 256) { w1s[e] = w1[e]; whs[e] = cwh[e]; wws[e] = cww[e]; }
    __syncthreads();

    float acc[8];
#pragma unroll
    for (int i = 0; i < 8; ++i) acc[i] = 0.f;
    for (int c = 0; c < Cn; ++c) {
        float yv = (p < Hn) ? xh[(b * Cn + c) * Hn + p] : xw[(b * Cn + c) * Wn + (p - Hn)];
#pragma unroll
        for (int mip = 0; mip < 8; ++mip) acc[mip] += w1s[mip * Cn + c] * yv;
    }
    float y2[8];
#pragma unroll
    for (int mip = 0; mip < 8; ++mip) {
        float sc = g[mip] * rsqrtf(v[mip] + EPSV);
        float t = (acc[mip] - m[mip]) * sc + bb[mip];
        y2[mip] = (t >= 0.f) ? t : aa[mip] * t;
    }
    const float* wsel = (p < Hn) ? whs : wws;
    float* osel = (p < Hn) ? a_h : a_w;
    int pp = (p < Hn) ? p : p - Hn;
    for (int c = 0; c < Cn; ++c) {
        float s = 0.f;
#pragma unroll
        for (int mip = 0; mip < 8; ++mip) s += wsel[c * 8 + mip] * y2[mip];
        osel[(b * Cn + c) * Hn + pp] = 1.f / (1.f + expf(-s));
    }
}

// ---------------------------------------------------------------------------
// K5: out = out_pre * a_h[b,c,h] * a_w[b,c,w]   (float4)
// ---------------------------------------------------------------------------
__global__ __launch_bounds__(256) void k5_final(
    const float* __restrict__ op, const float* __restrict__ a_h,
    const float* __restrict__ a_w, float* __restrict__ out)
{
    int idx = blockIdx.x * 256 + threadIdx.x;
    int e = idx * 4;
    if (e >= NIMG) return;
    int w = e & 127;
    int h = (e >> 7) & 127;
    int bc = e >> 14;
    float4 vv = *(const float4*)(op + e);
    float ah = a_h[bc * Hn + h];
    float4 aw = *(const float4*)(a_w + bc * Wn + w);
    float4 r;
    r.x = vv.x * ah * aw.x;
    r.y = vv.y * ah * aw.y;
    r.z = vv.z * ah * aw.z;
    r.w = vv.w * ah * aw.w;
    *(float4*)(out + e) = r;
}

// ---------------------------------------------------------------------------
extern "C" void kernel_launch(void* const* d_in, const int* in_sizes, int n_in,
                              void* d_out, int out_size, void* d_ws, size_t ws_size,
                              hipStream_t stream)
{
    const float* x     = (const float*)d_in[0];
    const float* r_m   = (const float*)d_in[1];
    const float* wh_m  = (const float*)d_in[2];
    const float* ww_m  = (const float*)d_in[3];
    const float* r_l   = (const float*)d_in[4];
    const float* wh_l  = (const float*)d_in[5];
    const float* ww_l  = (const float*)d_in[6];
    const float* wfuse = (const float*)d_in[7];
    const float* bnf_g = (const float*)d_in[8];
    const float* bnf_b = (const float*)d_in[9];
    const float* bnf_m = (const float*)d_in[10];
    const float* bnf_v = (const float*)d_in[11];
    const float* dg_wh = (const float*)d_in[12];
    const float* dg_ww = (const float*)d_in[13];
    const float* dg_g  = (const float*)d_in[14];
    const float* dg_b  = (const float*)d_in[15];
    const float* dg_m  = (const float*)d_in[16];
    const float* dg_v  = (const float*)d_in[17];
    const float* act_a = (const float*)d_in[18];
    const float* ca_w1 = (const float*)d_in[19];
    const float* ca_g  = (const float*)d_in[20];
    const float* ca_b  = (const float*)d_in[21];
    const float* ca_m  = (const float*)d_in[22];
    const float* ca_v  = (const float*)d_in[23];
    const float* ca_a  = (const float*)d_in[24];
    const float* ca_wh = (const float*)d_in[25];
    const float* ca_ww = (const float*)d_in[26];

    float* ws      = (float*)d_ws;
    float* t_buf   = ws;                     // NIMG
    float* out_pre = ws + (size_t)NIMG;      // NIMG
    float* xh      = out_pre + (size_t)NIMG; // B*C*H
    float* xw      = xh + Bn * Cn * Hn;
    float* a_h     = xw + Bn * Cn * Wn;
    float* a_w     = a_h + Bn * Cn * Hn;

    float* out = (float*)d_out;

    hipLaunchKernelGGL(k1_axial, dim3(NIMG / 256), dim3(256), 0, stream,
                       x, r_m, wh_m, ww_m, r_l, wh_l, ww_l, t_buf);
    hipLaunchKernelGGL(k2_pw, dim3(Bn * PLANE / 64), dim3(256), 0, stream,
                       t_buf, x, wfuse, bnf_g, bnf_b, bnf_m, bnf_v,
                       dg_wh, dg_ww, dg_g, dg_b, dg_m, dg_v, act_a, out_pre);
    hipLaunchKernelGGL(k3_means, dim3(Bn * Cn), dim3(128), 0, stream,
                       out_pre, xh, xw);
    hipLaunchKernelGGL(k4_att, dim3(Bn), dim3(256), 0, stream,
                       xh, xw, ca_w1, ca_g, ca_b, ca_m, ca_v, ca_a, ca_wh, ca_ww,
                       a_h, a_w);
    hipLaunchKernelGGL(k5_final, dim3(NIMG / 1024), dim3(256), 0, stream,
                       out_pre, a_h, a_w, out);
}